// Round 6
// baseline (8122.798 us; speedup 1.0000x reference)
//
#include <hip/hip_runtime.h>
#include <cstdint>
#include <cstddef>

typedef float f32x4 __attribute__((ext_vector_type(4)));
typedef __bf16 bf16x8 __attribute__((ext_vector_type(8)));
typedef unsigned int u32x4 __attribute__((ext_vector_type(4)));

#define T_STEPS 256
#define HD      1024
#define DHK     2048

__device__ __forceinline__ unsigned short f2bf(float f) {
  union { float f; unsigned u; } v; v.f = f;
  unsigned r = v.u + 0x7fffu + ((v.u >> 16) & 1u);  // RNE, inputs finite
  return (unsigned short)(r >> 16);
}

__device__ __forceinline__ float fast_sigmoid(float x) {
  return 1.0f / (1.0f + __expf(-x));
}
__device__ __forceinline__ float fast_tanh(float x) {
  float e = __expf(2.0f * x);
  return (e - 1.0f) / (e + 1.0f);
}

__device__ __forceinline__ f32x4 mfma16(bf16x8 a, bf16x8 b, f32x4 c) {
  return __builtin_amdgcn_mfma_f32_16x16x32_bf16(a, b, c, 0, 0, 0);
}

// ---- coherent data path (bypass L1/L2, served by MALL) ---------------------
#define LOADC(dst, vofs, base, IMM)                                            \
  asm volatile("global_load_dwordx4 %0, %1, %2 offset:" IMM " sc0 sc1"         \
               : "=v"(dst) : "v"(vofs), "s"(base) : "memory")

#define L8(st, vofs, base)                                                     \
  LOADC(st[0], vofs, base, "0");   LOADC(st[1], vofs, base, "64");             \
  LOADC(st[2], vofs, base, "128"); LOADC(st[3], vofs, base, "192");            \
  LOADC(st[4], vofs, base, "256"); LOADC(st[5], vofs, base, "320");            \
  LOADC(st[6], vofs, base, "384"); LOADC(st[7], vofs, base, "448")

#define WAITV0()                                                               \
  do { asm volatile("s_waitcnt vmcnt(0)" ::: "memory");                        \
       __builtin_amdgcn_sched_barrier(0); } while (0)

__device__ __forceinline__ void storec16(void* p, u32x4 v) {
  asm volatile("global_store_dwordx4 %0, %1, off sc0 sc1"
               :: "v"(p), "v"(v) : "memory");
}
__device__ __forceinline__ void storec4(void* p, unsigned v) {
  asm volatile("global_store_dword %0, %1, off sc0 sc1"
               :: "v"(p), "v"(v) : "memory");
}

__device__ __forceinline__ void release_flag(int* f, int v) {
  asm volatile("s_waitcnt vmcnt(0)" ::: "memory");
  __hip_atomic_store(f, v, __ATOMIC_RELAXED, __HIP_MEMORY_SCOPE_AGENT);
}
__device__ __forceinline__ void wait_ge(const int* f, int v) {
  while (__hip_atomic_load(f, __ATOMIC_RELAXED, __HIP_MEMORY_SCOPE_AGENT) < v)
    __builtin_amdgcn_s_sleep(2);
  asm volatile("" ::: "memory");
}

// ---- persistent kernel: 128 blocks x 256 threads, 32 output cols/block -----
//   A: G[gate*64+b][h]  = act(comb @ W^T + bias)   K=2048, 128 blk = 4g x 32ct
//   B: G2 = tanh(G @ qcw0^T + qcb0)                K=1024, 4 row-gates x 32ct
//   C: rows (gate,16-batch) -> cell update         K=1024, 4 batch-t x 32ct
// Weights: plain cached loads (compiler-managed waits; L2-resident).
__global__ __launch_bounds__(256, 1) void qlstm_persist(
    const unsigned short* __restrict__ Xbf,
    const unsigned short* __restrict__ Wbf,      // [4096][2048]
    const unsigned short* __restrict__ qcw,      // [2][1024][1024]
    const float* __restrict__ bias_cat,          // [4096]
    const float* __restrict__ qcb,               // [2][1024]
    unsigned short* __restrict__ Gbf,            // [256][1024]
    unsigned short* __restrict__ G2bf,           // [256][1024]
    unsigned short* __restrict__ hbf,            // [64][1024]
    float* __restrict__ c_state,                 // [64][1024]
    float* __restrict__ out,
    int* __restrict__ aA, int* __restrict__ aB, int* __restrict__ aC) {
  const int nb = blockIdx.x, tid = threadIdx.x;
  const int wv = tid >> 6, lane = tid & 63;
  const int l15 = lane & 15, l16 = lane >> 4;
  const int l16o = l16 * 8;
  const int q = nb >> 5;            // A/B: gate | C: batch-tile
  const int nsub = (nb & 31) * 32;  // col base within 1024
  const int kb = wv * 256;          // wave K-slice base

  __shared__ __align__(16) float red[4][32][68];  // [wave][col][row(padded)]

  // weight row pointers (kb folded in)
  const unsigned short* wA0 = Wbf + (size_t)(nb * 32 + l15) * DHK + kb;
  const unsigned short* wA1 = wA0 + (size_t)16 * DHK;
  const unsigned short* wB0 = qcw + (size_t)(nsub + l15) * HD + kb;
  const unsigned short* wB1 = wB0 + (size_t)16 * HD;
  const unsigned short* wC0 = wB0 + (size_t)HD * HD;
  const unsigned short* wC1 = wB1 + (size_t)HD * HD;

  // byte voffsets for coherent staging (step-invariant)
  int vofsAB[4], vofsC[4];
#pragma unroll
  for (int mt = 0; mt < 4; ++mt) {
    vofsAB[mt] = ((mt * 16 + l15) * HD + kb + l16o) * 2;
    vofsC[mt]  = ((mt * 64 + q * 16 + l15) * HD + kb + l16o) * 2;
  }

  const int erow = tid >> 2, ecb = (tid & 3) * 8;  // A/B epilogue coords
  const int bl = tid >> 4, cl = (tid & 15) * 2;    // C epilogue coords
  float bA[8], bB[8];
#pragma unroll
  for (int i = 0; i < 8; ++i) {
    bA[i] = bias_cat[nb * 32 + ecb + i];
    bB[i] = qcb[nsub + ecb + i];
  }
  const float bC0 = qcb[HD + nsub + cl], bC1 = qcb[HD + nsub + cl + 1];

  const unsigned short* hB = hbf;
  const unsigned short* gB = Gbf + (size_t)(q * 64) * HD;

  for (int t = 0; t < T_STEPS; ++t) {
    // ================= phase A: gates =================
    {
      f32x4 acc[4][2] = {};
      // x-half: independent of the recurrence -> overlaps handoff wait
      const unsigned short* xb = Xbf + (size_t)t * (64 * HD);
#pragma unroll
      for (int s = 0; s < 8; ++s) {
        bf16x8 w0 = *(const bf16x8*)&wA0[s * 32 + l16o];
        bf16x8 w1 = *(const bf16x8*)&wA1[s * 32 + l16o];
#pragma unroll
        for (int mt = 0; mt < 4; ++mt) {
          bf16x8 a =
              *(const bf16x8*)&xb[(size_t)(mt * 16 + l15) * HD + kb + s * 32 + l16o];
          acc[mt][0] = mfma16(a, w0, acc[mt][0]);
          acc[mt][1] = mfma16(a, w1, acc[mt][1]);
        }
      }
      if (tid < 128) wait_ge(&aC[tid], t);        // h(t-1) ready (all C blocks)
      __syncthreads();
      {
        bf16x8 st0[8], st1[8], st2[8], st3[8];
        L8(st0, vofsAB[0], hB); L8(st1, vofsAB[1], hB);
        L8(st2, vofsAB[2], hB); L8(st3, vofsAB[3], hB);
        WAITV0();
#pragma unroll
        for (int s = 0; s < 8; ++s) {
          bf16x8 w0 = *(const bf16x8*)&wA0[1024 + s * 32 + l16o];
          bf16x8 w1 = *(const bf16x8*)&wA1[1024 + s * 32 + l16o];
          acc[0][0] = mfma16(st0[s], w0, acc[0][0]);
          acc[0][1] = mfma16(st0[s], w1, acc[0][1]);
          acc[1][0] = mfma16(st1[s], w0, acc[1][0]);
          acc[1][1] = mfma16(st1[s], w1, acc[1][1]);
          acc[2][0] = mfma16(st2[s], w0, acc[2][0]);
          acc[2][1] = mfma16(st2[s], w1, acc[2][1]);
          acc[3][0] = mfma16(st3[s], w0, acc[3][0]);
          acc[3][1] = mfma16(st3[s], w1, acc[3][1]);
        }
      }
#pragma unroll
      for (int mt = 0; mt < 4; ++mt)
#pragma unroll
        for (int g = 0; g < 2; ++g)
          *(f32x4*)&red[wv][g * 16 + l15][mt * 16 + l16 * 4] = acc[mt][g];
      __syncthreads();
      union { u32x4 u4; unsigned short us[8]; } pk;
#pragma unroll
      for (int i = 0; i < 8; ++i) {
        const int c = ecb + i;
        float v = red[0][c][erow] + red[1][c][erow] +
                  red[2][c][erow] + red[3][c][erow] + bA[i];
        v = (q == 2) ? fast_tanh(v) : fast_sigmoid(v);
        pk.us[i] = f2bf(v);
      }
      storec16(&Gbf[(size_t)(q * 64 + erow) * HD + nsub + ecb], pk.u4);
      __syncthreads();
      if (tid == 0) release_flag(&aA[nb], t + 1);
    }
    // ================= phase B: qc depth 0 =================
    {
      if (tid < 32) wait_ge(&aA[q * 32 + tid], t + 1);  // our gate's producers
      __syncthreads();
      f32x4 acc[4][2] = {};
      {
        bf16x8 st0[8], st1[8], st2[8], st3[8];
        L8(st0, vofsAB[0], gB); L8(st1, vofsAB[1], gB);
        L8(st2, vofsAB[2], gB); L8(st3, vofsAB[3], gB);
        WAITV0();
#pragma unroll
        for (int s = 0; s < 8; ++s) {
          bf16x8 w0 = *(const bf16x8*)&wB0[s * 32 + l16o];
          bf16x8 w1 = *(const bf16x8*)&wB1[s * 32 + l16o];
          acc[0][0] = mfma16(st0[s], w0, acc[0][0]);
          acc[0][1] = mfma16(st0[s], w1, acc[0][1]);
          acc[1][0] = mfma16(st1[s], w0, acc[1][0]);
          acc[1][1] = mfma16(st1[s], w1, acc[1][1]);
          acc[2][0] = mfma16(st2[s], w0, acc[2][0]);
          acc[2][1] = mfma16(st2[s], w1, acc[2][1]);
          acc[3][0] = mfma16(st3[s], w0, acc[3][0]);
          acc[3][1] = mfma16(st3[s], w1, acc[3][1]);
        }
      }
#pragma unroll
      for (int mt = 0; mt < 4; ++mt)
#pragma unroll
        for (int g = 0; g < 2; ++g)
          *(f32x4*)&red[wv][g * 16 + l15][mt * 16 + l16 * 4] = acc[mt][g];
      __syncthreads();
      union { u32x4 u4; unsigned short us[8]; } pk;
#pragma unroll
      for (int i = 0; i < 8; ++i) {
        const int c = ecb + i;
        float v = red[0][c][erow] + red[1][c][erow] +
                  red[2][c][erow] + red[3][c][erow] + bB[i];
        pk.us[i] = f2bf(fast_tanh(v));
      }
      storec16(&G2bf[(size_t)(q * 64 + erow) * HD + nsub + ecb], pk.u4);
      __syncthreads();
      if (tid == 0) release_flag(&aB[nb], t + 1);
    }
    // ================= phase C: qc depth 1 + cell update =================
    {
      if (tid < 128) wait_ge(&aB[tid], t + 1);    // needs all of G2's K
      __syncthreads();
      f32x4 acc[4][2] = {};
      {
        bf16x8 st0[8], st1[8], st2[8], st3[8];
        L8(st0, vofsC[0], G2bf); L8(st1, vofsC[1], G2bf);
        L8(st2, vofsC[2], G2bf); L8(st3, vofsC[3], G2bf);
        WAITV0();
#pragma unroll
        for (int s = 0; s < 8; ++s) {
          bf16x8 w0 = *(const bf16x8*)&wC0[s * 32 + l16o];
          bf16x8 w1 = *(const bf16x8*)&wC1[s * 32 + l16o];
          acc[0][0] = mfma16(st0[s], w0, acc[0][0]);
          acc[0][1] = mfma16(st0[s], w1, acc[0][1]);
          acc[1][0] = mfma16(st1[s], w0, acc[1][0]);
          acc[1][1] = mfma16(st1[s], w1, acc[1][1]);
          acc[2][0] = mfma16(st2[s], w0, acc[2][0]);
          acc[2][1] = mfma16(st2[s], w1, acc[2][1]);
          acc[3][0] = mfma16(st3[s], w0, acc[3][0]);
          acc[3][1] = mfma16(st3[s], w1, acc[3][1]);
        }
      }
#pragma unroll
      for (int mt = 0; mt < 4; ++mt)
#pragma unroll
        for (int g = 0; g < 2; ++g)
          *(f32x4*)&red[wv][g * 16 + l15][mt * 16 + l16 * 4] = acc[mt][g];
      __syncthreads();
      float gv0[4], gv1[4];
#pragma unroll
      for (int g4 = 0; g4 < 4; ++g4) {
        float v0 = red[0][cl][g4 * 16 + bl] + red[1][cl][g4 * 16 + bl] +
                   red[2][cl][g4 * 16 + bl] + red[3][cl][g4 * 16 + bl] + bC0;
        float v1 = red[0][cl + 1][g4 * 16 + bl] + red[1][cl + 1][g4 * 16 + bl] +
                   red[2][cl + 1][g4 * 16 + bl] + red[3][cl + 1][g4 * 16 + bl] + bC1;
        gv0[g4] = fast_tanh(v0);
        gv1[g4] = fast_tanh(v1);
      }
      const int ci = (q * 16 + bl) * HD + nsub + cl;
      const float cn0 = gv0[0] * c_state[ci] + gv0[1] * gv0[2];
      const float cn1 = gv1[0] * c_state[ci + 1] + gv1[1] * gv1[2];
      const float hn0 = gv0[3] * fast_tanh(cn0);
      const float hn1 = gv1[3] * fast_tanh(cn1);
      c_state[ci] = cn0; c_state[ci + 1] = cn1;
      *(float2*)&out[(size_t)t * (64 * HD) + ci] = make_float2(hn0, hn1);
      unsigned hp = (unsigned)f2bf(hn0) | ((unsigned)f2bf(hn1) << 16);
      storec4(&hbf[ci], hp);
      if (t == T_STEPS - 1) {
        *(float2*)&out[(size_t)T_STEPS * (64 * HD) + ci] = make_float2(hn0, hn1);
        *(float2*)&out[(size_t)T_STEPS * (64 * HD) + 64 * HD + ci] =
            make_float2(cn0, cn1);
      }
      __syncthreads();
      if (tid == 0) release_flag(&aC[nb], t + 1);
    }
  }
}

// ---- prep kernels ----------------------------------------------------------
__global__ void xconv_kernel(const float* __restrict__ x,
                             unsigned short* __restrict__ xbf, int n4) {
  int idx = blockIdx.x * blockDim.x + threadIdx.x;
  int stride = gridDim.x * blockDim.x;
  for (int i = idx; i < n4; i += stride) {
    float4 v = ((const float4*)x)[i];
    ushort4 o;
    o.x = f2bf(v.x); o.y = f2bf(v.y); o.z = f2bf(v.z); o.w = f2bf(v.w);
    ((ushort4*)xbf)[i] = o;
  }
}

__global__ void wconv_kernel(const float* __restrict__ Wf, const float* __restrict__ Wi,
                             const float* __restrict__ Wu, const float* __restrict__ Wo,
                             const float* __restrict__ bfv, const float* __restrict__ biv,
                             const float* __restrict__ buv, const float* __restrict__ bov,
                             unsigned short* __restrict__ Wbf, float* __restrict__ bias_cat) {
  const int n = blockIdx.x;                 // 0..4095
  const int gate = n >> 10, r = n & 1023;
  const float* W = gate == 0 ? Wf : gate == 1 ? Wi : gate == 2 ? Wu : Wo;
  const float* src = W + (size_t)r * DHK;
  unsigned short* dst = Wbf + (size_t)n * DHK;
  for (int k = threadIdx.x; k < DHK; k += 256) dst[k] = f2bf(src[k]);
  if (threadIdx.x == 0) {
    const float* bsrc = gate == 0 ? bfv : gate == 1 ? biv : gate == 2 ? buv : bov;
    bias_cat[n] = bsrc[r];
  }
}

__global__ void qcw_kernel(const float* __restrict__ qcv, const float* __restrict__ qcg,
                           unsigned short* __restrict__ qcw) {
  const int row = blockIdx.x * 4 + (threadIdx.x >> 6);  // 0..2047 (= d*1024+o)
  const int lane = threadIdx.x & 63;
  const float* v = qcv + (size_t)row * HD;
  float ss = 0.0f;
#pragma unroll
  for (int j = 0; j < 16; ++j) { float a = v[j * 64 + lane]; ss += a * a; }
#pragma unroll
  for (int off = 32; off > 0; off >>= 1) ss += __shfl_xor(ss, off);
  const float scale = qcg[row] / sqrtf(ss);
#pragma unroll
  for (int j = 0; j < 16; ++j)
    qcw[(size_t)row * HD + j * 64 + lane] = f2bf(v[j * 64 + lane] * scale);
}

__global__ void init_state_kernel(unsigned short* __restrict__ hbf,
                                  float* __restrict__ c_state,
                                  int* __restrict__ flags) {
  int i = blockIdx.x * blockDim.x + threadIdx.x;  // 65536 launched
  hbf[i] = 0;
  c_state[i] = 0.0f;
  if (i < 384) flags[i] = 0;
}

// ---- launcher --------------------------------------------------------------
extern "C" void kernel_launch(void* const* d_in, const int* in_sizes, int n_in,
                              void* d_out, int out_size, void* d_ws, size_t ws_size,
                              hipStream_t stream) {
  const float* x   = (const float*)d_in[0];
  const float* Wf  = (const float*)d_in[1];
  const float* bfv = (const float*)d_in[2];
  const float* Wi  = (const float*)d_in[3];
  const float* biv = (const float*)d_in[4];
  const float* Wu  = (const float*)d_in[5];
  const float* buv = (const float*)d_in[6];
  const float* Wo  = (const float*)d_in[7];
  const float* bov = (const float*)d_in[8];
  const float* qcv = (const float*)d_in[9];
  const float* qcg = (const float*)d_in[10];
  const float* qcb = (const float*)d_in[11];
  float* out = (float*)d_out;

  char* p = (char*)d_ws;
  auto alloc = [&](size_t bytes) {
    char* r = p; p += (bytes + 255) & ~(size_t)255; return r;
  };
  unsigned short* Xbf  = (unsigned short*)alloc((size_t)T_STEPS * 64 * HD * 2);
  unsigned short* Wbf  = (unsigned short*)alloc((size_t)4096 * DHK * 2);
  unsigned short* qcw  = (unsigned short*)alloc((size_t)2 * HD * HD * 2);
  float* bias_cat      = (float*)alloc((size_t)4096 * 4);
  unsigned short* Gbf  = (unsigned short*)alloc((size_t)256 * HD * 2);
  unsigned short* G2bf = (unsigned short*)alloc((size_t)256 * HD * 2);
  unsigned short* hbf  = (unsigned short*)alloc((size_t)64 * HD * 2);
  float* c_state       = (float*)alloc((size_t)64 * HD * 4);
  int* flags           = (int*)alloc(384 * 4);

  init_state_kernel<<<256, 256, 0, stream>>>(hbf, c_state, flags);
  xconv_kernel<<<2048, 256, 0, stream>>>(x, Xbf, T_STEPS * 64 * HD / 4);
  wconv_kernel<<<4096, 256, 0, stream>>>(Wf, Wi, Wu, Wo, bfv, biv, buv, bov,
                                         Wbf, bias_cat);
  qcw_kernel<<<512, 256, 0, stream>>>(qcv, qcg, qcw);

  qlstm_persist<<<128, 256, 0, stream>>>(
      Xbf, Wbf, qcw, bias_cat, qcb, Gbf, G2bf, hbf, c_state, out,
      flags, flags + 128, flags + 256);
}

// Round 7
// 6636.967 us; speedup vs baseline: 1.2239x; 1.2239x over previous
//
#include <hip/hip_runtime.h>
#include <cstdint>
#include <cstddef>

typedef float f32x4 __attribute__((ext_vector_type(4)));
typedef __bf16 bf16x8 __attribute__((ext_vector_type(8)));
typedef unsigned int u32x4 __attribute__((ext_vector_type(4)));

#define T_STEPS 256
#define HD      1024
#define DHK     2048

// dynamic LDS: 32 fragment-slots x 256 threads x 16B weights, then reduce buf
#define LDSW_BYTES (32 * 256 * 16)
#define LDS_TOTAL  (LDSW_BYTES + 4 * 16 * 68 * 4)

__device__ __forceinline__ unsigned short f2bf(float f) {
  union { float f; unsigned u; } v; v.f = f;
  unsigned r = v.u + 0x7fffu + ((v.u >> 16) & 1u);  // RNE, inputs finite
  return (unsigned short)(r >> 16);
}

__device__ __forceinline__ float fast_sigmoid(float x) {
  return 1.0f / (1.0f + __expf(-x));
}
__device__ __forceinline__ float fast_tanh(float x) {
  float e = __expf(2.0f * x);
  return (e - 1.0f) / (e + 1.0f);
}

__device__ __forceinline__ f32x4 mfma16(bf16x8 a, bf16x8 b, f32x4 c) {
  return __builtin_amdgcn_mfma_f32_16x16x32_bf16(a, b, c, 0, 0, 0);
}

// ---- coherent data path (bypass L1/L2, served by the LLC) ------------------
#define LOADC(dst, vofs, base, IMM)                                            \
  asm volatile("global_load_dwordx4 %0, %1, %2 offset:" IMM " sc0 sc1"         \
               : "=v"(dst) : "v"(vofs), "s"(base) : "memory")

#define L8(st, vofs, base)                                                     \
  LOADC(st[0], vofs, base, "0");   LOADC(st[1], vofs, base, "64");             \
  LOADC(st[2], vofs, base, "128"); LOADC(st[3], vofs, base, "192");            \
  LOADC(st[4], vofs, base, "256"); LOADC(st[5], vofs, base, "320");            \
  LOADC(st[6], vofs, base, "384"); LOADC(st[7], vofs, base, "448")

#define WAITV0()                                                               \
  do { asm volatile("s_waitcnt vmcnt(0)" ::: "memory");                        \
       __builtin_amdgcn_sched_barrier(0); } while (0)

__device__ __forceinline__ void storec8(void* p, ushort4 v) {
  asm volatile("global_store_dwordx2 %0, %1, off sc0 sc1"
               :: "v"(p), "v"(v) : "memory");
}
__device__ __forceinline__ void storec2(void* p, unsigned short v) {
  unsigned vv = v;
  asm volatile("global_store_short %0, %1, off sc0 sc1"
               :: "v"(p), "v"(vv) : "memory");
}

__device__ __forceinline__ void release_flag(int* f, int v) {
  asm volatile("s_waitcnt vmcnt(0)" ::: "memory");
  __hip_atomic_store(f, v, __ATOMIC_RELAXED, __HIP_MEMORY_SCOPE_AGENT);
}
__device__ __forceinline__ void wait_ge(const int* f, int v) {
  while (__hip_atomic_load(f, __ATOMIC_RELAXED, __HIP_MEMORY_SCOPE_AGENT) < v)
    __builtin_amdgcn_s_sleep(1);
  asm volatile("" ::: "memory");
}

// ---- persistent kernel: 256 blocks x 256 threads, 16 output cols/block -----
//   A: G[gate*64+b][h]  = act(comb @ W^T + bias)   K=2048
//   B: G2 = tanh(G @ qcw0^T + qcb0)                K=1024
//   C: rows (gate,16-batch) -> cell update         K=1024
// Weights staged ONCE into LDS in per-thread fragment order lw[j*256+tid]:
//   j 0..7 = A x-half, 8..15 = A h-half, 16..23 = B, 24..31 = C.
// Lanes are contiguous 16B slots -> conflict-free ds_read_b128 every phase.
__global__ __launch_bounds__(256, 1) void qlstm_persist(
    const unsigned short* __restrict__ Xbf,
    const unsigned short* __restrict__ Wbf,      // [4096][2048]
    const unsigned short* __restrict__ qcw,      // [2][1024][1024]
    const float* __restrict__ bias_cat,          // [4096]
    const float* __restrict__ qcb,               // [2][1024]
    unsigned short* __restrict__ Gbf,            // [256][1024]
    unsigned short* __restrict__ G2bf,           // [256][1024]
    unsigned short* __restrict__ hbf,            // [64][1024]
    float* __restrict__ c_state,                 // [64][1024]
    float* __restrict__ out,
    int* __restrict__ aA, int* __restrict__ aB, int* __restrict__ aC) {
  extern __shared__ char lds_raw[];
  uint4* lw = (uint4*)lds_raw;
  float* red = (float*)(lds_raw + LDSW_BYTES);   // [4][16][68]

  const int nb = blockIdx.x, tid = threadIdx.x;
  const int wv = tid >> 6, lane = tid & 63;
  const int l15 = lane & 15, l16 = lane >> 4;
  const int l16o = l16 * 8;
  const int q = nb >> 6;            // A: gate | B: row-gate | C: batch-tile
  const int n0 = (nb & 63) * 16;    // col offset within 1024
  const int kb = wv * 256;          // wave K-slice base

  // ---- stage weights into LDS (once) ----
  {
    const unsigned short* wArow = Wbf + (size_t)(nb * 16 + l15) * DHK + kb + l16o;
    const unsigned short* wBrow = qcw + (size_t)(n0 + l15) * HD + kb + l16o;
    const unsigned short* wCrow = wBrow + (size_t)HD * HD;
#pragma unroll
    for (int s = 0; s < 8; ++s) {
      lw[s * 256 + tid]        = *(const uint4*)&wArow[s * 32];
      lw[(8 + s) * 256 + tid]  = *(const uint4*)&wArow[1024 + s * 32];
      lw[(16 + s) * 256 + tid] = *(const uint4*)&wBrow[s * 32];
      lw[(24 + s) * 256 + tid] = *(const uint4*)&wCrow[s * 32];
    }
  }
  __syncthreads();

  const int erow = tid >> 2, ecb = (tid & 3) * 4;  // A/B epilogue coords
  const int bl = tid >> 4, cc = tid & 15;          // C epilogue coords
  f32x4 biasA, biasB;
#pragma unroll
  for (int i = 0; i < 4; ++i) {
    biasA[i] = bias_cat[nb * 16 + ecb + i];
    biasB[i] = qcb[n0 + ecb + i];
  }
  const float biasC = qcb[HD + n0 + cc];

  // byte voffsets for coherent staging loads (step-invariant)
  int vofsAB[4], vofsC[4];
#pragma unroll
  for (int mt = 0; mt < 4; ++mt) {
    vofsAB[mt] = ((mt * 16 + l15) * HD + kb + l16o) * 2;
    vofsC[mt]  = ((mt * 64 + q * 16 + l15) * HD + kb + l16o) * 2;
  }
  const unsigned short* hB = hbf;
  const unsigned short* gB = Gbf + (size_t)(q * 64) * HD;

  for (int t = 0; t < T_STEPS; ++t) {
    // ================= phase A: gates =================
    {
      f32x4 acc[4] = {};
      // x-half: independent of the recurrence -> overlaps handoff wait
      const unsigned short* xb = Xbf + (size_t)t * (64 * HD);
#pragma unroll
      for (int s = 0; s < 8; ++s) {
        bf16x8 w = *(const bf16x8*)&lw[s * 256 + tid];
#pragma unroll
        for (int mt = 0; mt < 4; ++mt) {
          bf16x8 a =
              *(const bf16x8*)&xb[(size_t)(mt * 16 + l15) * HD + kb + s * 32 + l16o];
          acc[mt] = mfma16(a, w, acc[mt]);
        }
      }
      wait_ge(&aC[tid], t);                       // h(t-1) ready (all C blocks)
      __syncthreads();
      {
        bf16x8 st0[8], st1[8], st2[8], st3[8];
        L8(st0, vofsAB[0], hB); L8(st1, vofsAB[1], hB);
        L8(st2, vofsAB[2], hB); L8(st3, vofsAB[3], hB);
        WAITV0();
#pragma unroll
        for (int s = 0; s < 8; ++s) {
          bf16x8 w = *(const bf16x8*)&lw[(8 + s) * 256 + tid];
          acc[0] = mfma16(st0[s], w, acc[0]);
          acc[1] = mfma16(st1[s], w, acc[1]);
          acc[2] = mfma16(st2[s], w, acc[2]);
          acc[3] = mfma16(st3[s], w, acc[3]);
        }
      }
#pragma unroll
      for (int mt = 0; mt < 4; ++mt)
        *(f32x4*)&red[(wv * 16 + l15) * 68 + mt * 16 + l16 * 4] = acc[mt];
      __syncthreads();
      ushort4 pk;
#pragma unroll
      for (int i = 0; i < 4; ++i) {
        const int c = ecb + i;
        float v = red[(0 * 16 + c) * 68 + erow] + red[(1 * 16 + c) * 68 + erow] +
                  red[(2 * 16 + c) * 68 + erow] + red[(3 * 16 + c) * 68 + erow] +
                  biasA[i];
        v = (q == 2) ? fast_tanh(v) : fast_sigmoid(v);
        ((unsigned short*)&pk)[i] = f2bf(v);
      }
      storec8(&Gbf[(size_t)(q * 64 + erow) * HD + n0 + ecb], pk);
      __syncthreads();
      if (tid == 0) release_flag(&aA[nb], t + 1);
    }
    // ================= phase B: qc depth 0 =================
    {
      if (tid < 64) wait_ge(&aA[q * 64 + tid], t + 1);  // our gate's producers
      __syncthreads();
      f32x4 acc[4] = {};
      {
        bf16x8 st0[8], st1[8], st2[8], st3[8];
        L8(st0, vofsAB[0], gB); L8(st1, vofsAB[1], gB);
        L8(st2, vofsAB[2], gB); L8(st3, vofsAB[3], gB);
        WAITV0();
#pragma unroll
        for (int s = 0; s < 8; ++s) {
          bf16x8 w = *(const bf16x8*)&lw[(16 + s) * 256 + tid];
          acc[0] = mfma16(st0[s], w, acc[0]);
          acc[1] = mfma16(st1[s], w, acc[1]);
          acc[2] = mfma16(st2[s], w, acc[2]);
          acc[3] = mfma16(st3[s], w, acc[3]);
        }
      }
#pragma unroll
      for (int mt = 0; mt < 4; ++mt)
        *(f32x4*)&red[(wv * 16 + l15) * 68 + mt * 16 + l16 * 4] = acc[mt];
      __syncthreads();
      ushort4 pk;
#pragma unroll
      for (int i = 0; i < 4; ++i) {
        const int c = ecb + i;
        float v = red[(0 * 16 + c) * 68 + erow] + red[(1 * 16 + c) * 68 + erow] +
                  red[(2 * 16 + c) * 68 + erow] + red[(3 * 16 + c) * 68 + erow] +
                  biasB[i];
        ((unsigned short*)&pk)[i] = f2bf(fast_tanh(v));
      }
      storec8(&G2bf[(size_t)(q * 64 + erow) * HD + n0 + ecb], pk);
      __syncthreads();
      if (tid == 0) release_flag(&aB[nb], t + 1);
    }
    // ================= phase C: qc depth 1 + cell update =================
    {
      wait_ge(&aB[tid], t + 1);                   // needs all of G2's K
      __syncthreads();
      f32x4 acc[4] = {};
      {
        bf16x8 st0[8], st1[8], st2[8], st3[8];
        L8(st0, vofsC[0], G2bf); L8(st1, vofsC[1], G2bf);
        L8(st2, vofsC[2], G2bf); L8(st3, vofsC[3], G2bf);
        WAITV0();
#pragma unroll
        for (int s = 0; s < 8; ++s) {
          bf16x8 w = *(const bf16x8*)&lw[(24 + s) * 256 + tid];
          acc[0] = mfma16(st0[s], w, acc[0]);
          acc[1] = mfma16(st1[s], w, acc[1]);
          acc[2] = mfma16(st2[s], w, acc[2]);
          acc[3] = mfma16(st3[s], w, acc[3]);
        }
      }
#pragma unroll
      for (int mt = 0; mt < 4; ++mt)
        *(f32x4*)&red[(wv * 16 + l15) * 68 + mt * 16 + l16 * 4] = acc[mt];
      __syncthreads();
      float gv[4];
#pragma unroll
      for (int g = 0; g < 4; ++g) {
        const int r = g * 16 + bl;
        float v = red[(0 * 16 + cc) * 68 + r] + red[(1 * 16 + cc) * 68 + r] +
                  red[(2 * 16 + cc) * 68 + r] + red[(3 * 16 + cc) * 68 + r] +
                  biasC;
        gv[g] = fast_tanh(v);
      }
      const int ci = (q * 16 + bl) * HD + n0 + cc;
      const float c_new = gv[0] * c_state[ci] + gv[1] * gv[2];
      const float h_new = gv[3] * fast_tanh(c_new);
      c_state[ci] = c_new;
      out[(size_t)t * (64 * HD) + ci] = h_new;
      storec2(&hbf[ci], f2bf(h_new));
      if (t == T_STEPS - 1) {
        out[(size_t)T_STEPS * (64 * HD) + ci] = h_new;             // hx
        out[(size_t)T_STEPS * (64 * HD) + 64 * HD + ci] = c_new;   // cx
      }
      __syncthreads();
      if (tid == 0) release_flag(&aC[nb], t + 1);
    }
  }
}

// ---- prep kernels ----------------------------------------------------------
__global__ void xconv_kernel(const float* __restrict__ x,
                             unsigned short* __restrict__ xbf, int n4) {
  int idx = blockIdx.x * blockDim.x + threadIdx.x;
  int stride = gridDim.x * blockDim.x;
  for (int i = idx; i < n4; i += stride) {
    float4 v = ((const float4*)x)[i];
    ushort4 o;
    o.x = f2bf(v.x); o.y = f2bf(v.y); o.z = f2bf(v.z); o.w = f2bf(v.w);
    ((ushort4*)xbf)[i] = o;
  }
}

__global__ void wconv_kernel(const float* __restrict__ Wf, const float* __restrict__ Wi,
                             const float* __restrict__ Wu, const float* __restrict__ Wo,
                             const float* __restrict__ bfv, const float* __restrict__ biv,
                             const float* __restrict__ buv, const float* __restrict__ bov,
                             unsigned short* __restrict__ Wbf, float* __restrict__ bias_cat) {
  const int n = blockIdx.x;                 // 0..4095
  const int gate = n >> 10, r = n & 1023;
  const float* W = gate == 0 ? Wf : gate == 1 ? Wi : gate == 2 ? Wu : Wo;
  const float* src = W + (size_t)r * DHK;
  unsigned short* dst = Wbf + (size_t)n * DHK;
  for (int k = threadIdx.x; k < DHK; k += 256) dst[k] = f2bf(src[k]);
  if (threadIdx.x == 0) {
    const float* bsrc = gate == 0 ? bfv : gate == 1 ? biv : gate == 2 ? buv : bov;
    bias_cat[n] = bsrc[r];
  }
}

__global__ void qcw_kernel(const float* __restrict__ qcv, const float* __restrict__ qcg,
                           unsigned short* __restrict__ qcw) {
  const int row = blockIdx.x * 4 + (threadIdx.x >> 6);  // 0..2047 (= d*1024+o)
  const int lane = threadIdx.x & 63;
  const float* v = qcv + (size_t)row * HD;
  float ss = 0.0f;
#pragma unroll
  for (int j = 0; j < 16; ++j) { float a = v[j * 64 + lane]; ss += a * a; }
#pragma unroll
  for (int off = 32; off > 0; off >>= 1) ss += __shfl_xor(ss, off);
  const float scale = qcg[row] / sqrtf(ss);
#pragma unroll
  for (int j = 0; j < 16; ++j)
    qcw[(size_t)row * HD + j * 64 + lane] = f2bf(v[j * 64 + lane] * scale);
}

__global__ void init_state_kernel(unsigned short* __restrict__ hbf,
                                  float* __restrict__ c_state,
                                  int* __restrict__ flags) {
  int i = blockIdx.x * blockDim.x + threadIdx.x;  // 65536 launched
  hbf[i] = 0;
  c_state[i] = 0.0f;
  if (i < 768) flags[i] = 0;
}

// ---- launcher --------------------------------------------------------------
extern "C" void kernel_launch(void* const* d_in, const int* in_sizes, int n_in,
                              void* d_out, int out_size, void* d_ws, size_t ws_size,
                              hipStream_t stream) {
  const float* x   = (const float*)d_in[0];
  const float* Wf  = (const float*)d_in[1];
  const float* bfv = (const float*)d_in[2];
  const float* Wi  = (const float*)d_in[3];
  const float* biv = (const float*)d_in[4];
  const float* Wu  = (const float*)d_in[5];
  const float* buv = (const float*)d_in[6];
  const float* Wo  = (const float*)d_in[7];
  const float* bov = (const float*)d_in[8];
  const float* qcv = (const float*)d_in[9];
  const float* qcg = (const float*)d_in[10];
  const float* qcb = (const float*)d_in[11];
  float* out = (float*)d_out;

  char* p = (char*)d_ws;
  auto alloc = [&](size_t bytes) {
    char* r = p; p += (bytes + 255) & ~(size_t)255; return r;
  };
  unsigned short* Xbf  = (unsigned short*)alloc((size_t)T_STEPS * 64 * HD * 2);
  unsigned short* Wbf  = (unsigned short*)alloc((size_t)4096 * DHK * 2);
  unsigned short* qcw  = (unsigned short*)alloc((size_t)2 * HD * HD * 2);
  float* bias_cat      = (float*)alloc((size_t)4096 * 4);
  unsigned short* Gbf  = (unsigned short*)alloc((size_t)256 * HD * 2);
  unsigned short* G2bf = (unsigned short*)alloc((size_t)256 * HD * 2);
  unsigned short* hbf  = (unsigned short*)alloc((size_t)64 * HD * 2);
  float* c_state       = (float*)alloc((size_t)64 * HD * 4);
  int* flags           = (int*)alloc(768 * 4);

  static int lds_set = 0;
  if (!lds_set) {
    hipFuncSetAttribute((const void*)qlstm_persist,
                        hipFuncAttributeMaxDynamicSharedMemorySize, LDS_TOTAL);
    lds_set = 1;
  }

  init_state_kernel<<<256, 256, 0, stream>>>(hbf, c_state, flags);
  xconv_kernel<<<2048, 256, 0, stream>>>(x, Xbf, T_STEPS * 64 * HD / 4);
  wconv_kernel<<<4096, 256, 0, stream>>>(Wf, Wi, Wu, Wo, bfv, biv, buv, bov,
                                         Wbf, bias_cat);
  qcw_kernel<<<512, 256, 0, stream>>>(qcv, qcg, qcw);

  qlstm_persist<<<256, 256, LDS_TOTAL, stream>>>(
      Xbf, Wbf, qcw, bias_cat, qcb, Gbf, G2bf, hbf, c_state, out,
      flags, flags + 256, flags + 512);
}